// Round 2
// baseline (241.446 us; speedup 1.0000x reference)
//
#include <hip/hip_runtime.h>
#include <hip/hip_bf16.h>

// Fused adapter: out = relu(LN(x) @ Wd + bd) @ Wu + bu
// LN folded into GEMM1:  down = rs*(x @ (gamma⊙Wd)) - rs*mu*s + t
//   s[k] = sum_d gamma[d]*Wd[d][k];  t[k] = sum_d beta[d]*Wd[d][k] + bd[k]
// R2 changes vs R1:
//  - prep kernel parallelized (was ~160us serial-loop + scattered 2B writes)
//  - BM 32->16: LDS 54.8KB -> ~27KB, occupancy 20% -> ~60-75%

#define D_MODEL 768
#define KB      64
#define BM      16      // rows per block
#define NTHR    256     // 4 waves

typedef __attribute__((ext_vector_type(8))) short    bf16x8;
typedef __attribute__((ext_vector_type(4))) float    f32x4;
typedef __attribute__((ext_vector_type(4))) unsigned short us4;

static __device__ __forceinline__ unsigned short f2bf(float f) {
  unsigned int u = __builtin_bit_cast(unsigned int, f);
  unsigned int r = u + 0x7FFFu + ((u >> 16) & 1u);
  return (unsigned short)(r >> 16);
}

// ---------------- prep kernel ----------------
// blocks 0..191 (256 thr): flat-coalesced writes of both transposed weights
//   wdT[k][d] = bf16(gamma[d]*Wd[d][k])  (64 x 768), flat i = k*768+d
//   wuT[d][k] = bf16(Wu[k][d])           (768 x 64), flat i = d*64+k
// block 192: s[k], t[k] via 4-way-per-k partial sums + LDS combine
__global__ void adapter_prep(const float* __restrict__ wd,
                             const float* __restrict__ wu,
                             const float* __restrict__ gamma,
                             const float* __restrict__ beta,
                             const float* __restrict__ bdown,
                             unsigned short* __restrict__ wdT,
                             unsigned short* __restrict__ wuT,
                             float* __restrict__ s_arr,
                             float* __restrict__ t_arr) {
  const int b = blockIdx.x;
  const int t = threadIdx.x;
  if (b < 192) {
    const int i = b * 256 + t;          // 0..49151
    // wdT: i = k*768 + d
    const int k1 = i / D_MODEL;
    const int d1 = i - k1 * D_MODEL;
    wdT[i] = f2bf(gamma[d1] * wd[(size_t)d1 * KB + k1]);
    // wuT: i = d*64 + k
    const int d2 = i >> 6;
    const int k2 = i & 63;
    wuT[i] = f2bf(wu[(size_t)k2 * D_MODEL + d2]);
  } else {
    // s,t: thread (k = t&63, c = t>>6) sums 192 d's; coalesced wd reads
    const int k = t & 63;
    const int c = t >> 6;
    float ss = 0.f, tt = 0.f;
    const int d0 = c * 192;
    #pragma unroll 4
    for (int d = d0; d < d0 + 192; ++d) {
      const float w = wd[(size_t)d * KB + k];
      ss = fmaf(gamma[d], w, ss);
      tt = fmaf(beta[d],  w, tt);
    }
    __shared__ float ps[4][64], pt[4][64];
    ps[c][k] = ss; pt[c][k] = tt;
    __syncthreads();
    if (t < 64) {
      s_arr[t] = ps[0][t] + ps[1][t] + ps[2][t] + ps[3][t];
      t_arr[t] = pt[0][t] + pt[1][t] + pt[2][t] + pt[3][t] + bdown[t];
    }
  }
}

// ---------------- main fused kernel ----------------
#define XPAD 776   // 768 + 8 bf16: row stride 1552 B (16B-aligned, bank+4/row)
#define PPAD 72    // 64 + 8

__global__ void __launch_bounds__(NTHR, 6) adapter_main(
    const float* __restrict__ x,
    const float* __restrict__ s_arr,
    const float* __restrict__ t_arr,
    const unsigned short* __restrict__ wdT,
    const unsigned short* __restrict__ wuT,
    const float* __restrict__ b_up,
    float* __restrict__ out) {

  __shared__ unsigned short x_s[BM * XPAD];   // 24.25 KiB
  __shared__ unsigned short p_s[BM * PPAD];   //  2.25 KiB
  __shared__ float mu_s[BM];
  __shared__ float rs_s[BM];

  const int t    = threadIdx.x;
  const int row0 = blockIdx.x * BM;

  // ---- Phase 1: load x tile (f32x4 coalesced), row stats, stage bf16 ----
  {
    const int r  = t >> 4;          // 16 threads per row
    const int c0 = (t & 15) * 4;    // stride 64
    const float* xp = x + (size_t)(row0 + r) * D_MODEL;
    float s1 = 0.f, s2 = 0.f;
    #pragma unroll
    for (int i = 0; i < 12; ++i) {
      const int c = c0 + 64 * i;
      const float4 v = *(const float4*)(xp + c);
      s1 += v.x + v.y + v.z + v.w;
      s2 = fmaf(v.x, v.x, s2); s2 = fmaf(v.y, v.y, s2);
      s2 = fmaf(v.z, v.z, s2); s2 = fmaf(v.w, v.w, s2);
      us4 pk;
      pk.x = f2bf(v.x); pk.y = f2bf(v.y); pk.z = f2bf(v.z); pk.w = f2bf(v.w);
      *(us4*)&x_s[r * XPAD + c] = pk;
    }
    // reduce across the 16 contiguous lanes sharing this row
    s1 += __shfl_xor(s1, 1); s2 += __shfl_xor(s2, 1);
    s1 += __shfl_xor(s1, 2); s2 += __shfl_xor(s2, 2);
    s1 += __shfl_xor(s1, 4); s2 += __shfl_xor(s2, 4);
    s1 += __shfl_xor(s1, 8); s2 += __shfl_xor(s2, 8);
    const float mean = s1 * (1.0f / 768.0f);
    const float var  = s2 * (1.0f / 768.0f) - mean * mean;
    if ((t & 15) == 0) {
      mu_s[r] = mean;
      rs_s[r] = rsqrtf(var + 1e-5f);
    }
  }
  __syncthreads();

  const int w  = t >> 6;       // wave 0..3
  const int l  = t & 63;
  const int lr = l & 15;
  const int lg = l >> 4;

  // ---- Phase 2: GEMM1 (x[16x768] @ WdT-as-B); wave w owns cols 16w..16w+15 ----
  {
    const int cw = 16 * w;
    f32x4 acc = {0.f, 0.f, 0.f, 0.f};
    const unsigned short* bp = wdT + (size_t)(cw + lr) * D_MODEL + 8 * lg;
    #pragma unroll
    for (int kk = 0; kk < 24; ++kk) {
      const bf16x8 bq = *(const bf16x8*)(bp + 32 * kk);
      const bf16x8 a0 = *(const bf16x8*)&x_s[lr * XPAD + 32 * kk + 8 * lg];
      acc = __builtin_amdgcn_mfma_f32_16x16x32_bf16(a0, bq, acc, 0, 0, 0);
    }
    const float sk = s_arr[cw + lr];
    const float tk = t_arr[cw + lr];
    #pragma unroll
    for (int j = 0; j < 4; ++j) {
      const int r = 4 * lg + j;                 // C/D row = (lane>>4)*4 + reg
      const float rs = rs_s[r], mu = mu_s[r];
      float dn = fmaf(rs, acc[j], fmaf(-rs * mu, sk, tk));
      dn = fmaxf(dn, 0.0f);
      p_s[r * PPAD + cw + lr] = f2bf(dn);
    }
  }
  __syncthreads();

  // ---- Phase 3: GEMM2 (P[16x64] @ WuT-as-B); wave w owns N-tiles 12w..12w+11 ----
  {
    const bf16x8 pa0 = *(const bf16x8*)&p_s[lr * PPAD + 8 * lg];
    const bf16x8 pa1 = *(const bf16x8*)&p_s[lr * PPAD + 32 + 8 * lg];
    #pragma unroll
    for (int i = 0; i < 12; ++i) {
      const int cn = 16 * (12 * w + i);
      const unsigned short* bp2 = wuT + (size_t)(cn + lr) * KB + 8 * lg;
      const bf16x8 b0 = *(const bf16x8*)(bp2);
      const bf16x8 b1 = *(const bf16x8*)(bp2 + 32);
      f32x4 c0 = {0.f, 0.f, 0.f, 0.f};
      c0 = __builtin_amdgcn_mfma_f32_16x16x32_bf16(pa0, b0, c0, 0, 0, 0);
      c0 = __builtin_amdgcn_mfma_f32_16x16x32_bf16(pa1, b1, c0, 0, 0, 0);
      const float bu = b_up[cn + lr];
      #pragma unroll
      for (int j = 0; j < 4; ++j) {
        out[(size_t)(row0 + 4 * lg + j) * D_MODEL + cn + lr] = c0[j] + bu;
      }
    }
  }
}

// ---------------- launch ----------------
extern "C" void kernel_launch(void* const* d_in, const int* in_sizes, int n_in,
                              void* d_out, int out_size, void* d_ws, size_t ws_size,
                              hipStream_t stream) {
  const float* x     = (const float*)d_in[0];
  const float* gamma = (const float*)d_in[1];
  const float* beta  = (const float*)d_in[2];
  const float* wd    = (const float*)d_in[3];
  const float* bdown = (const float*)d_in[4];
  const float* wu    = (const float*)d_in[5];
  const float* bup   = (const float*)d_in[6];
  float* out = (float*)d_out;

  char* ws = (char*)d_ws;
  unsigned short* wdT = (unsigned short*)ws;                    // 96 KiB
  unsigned short* wuT = (unsigned short*)(ws + 98304);          // 96 KiB
  float* s_arr = (float*)(ws + 196608);                         // 256 B
  float* t_arr = (float*)(ws + 196864);                         // 256 B

  const int rows = in_sizes[0] / D_MODEL;       // 32768

  adapter_prep<<<193, NTHR, 0, stream>>>(wd, wu, gamma, beta, bdown,
                                         wdT, wuT, s_arr, t_arr);
  adapter_main<<<rows / BM, NTHR, 0, stream>>>(x, s_arr, t_arr, wdT, wuT, bup, out);
}

// Round 3
// 224.549 us; speedup vs baseline: 1.0752x; 1.0752x over previous
//
#include <hip/hip_runtime.h>
#include <hip/hip_bf16.h>

// Fused adapter: out = relu(LN(x) @ Wd + bd) @ Wu + bu
// LN folded into GEMM1:  down = rs*(x @ (gamma⊙Wd)) - rs*mu*s + t
//   s[k] = sum_d gamma[d]*Wd[d][k];  t[k] = sum_d beta[d]*Wd[d][k] + bd[k]
// R3: per-wave streaming structure (R2 was latency-bound at ~2 TB/s with
// lockstep barrier phases):
//  - each wave owns a 16-row tile end-to-end; no x staging in LDS
//  - GEMM1 swapped: mfma(A=WdT, B=x_frag) -> down^T; x loaded HBM->reg once,
//    LN stats accumulated in the same loop, lane-local in swapped C layout
//  - P (16x64) bounced through 2.25 KiB/wave LDS to re-fragment for GEMM2
//  - out stores complete each 128B line in adjacent iterations (R2 showed
//    1.4x write amplification from split partial-line stores)

#define D_MODEL 768
#define KB      64
#define NTHR    256     // 4 waves, each an independent 16-row tile
#define PPAD    72      // 64 + 8 bf16 pad

typedef __attribute__((ext_vector_type(8))) short    bf16x8;
typedef __attribute__((ext_vector_type(4))) float    f32x4;
typedef __attribute__((ext_vector_type(4))) unsigned short us4;

static __device__ __forceinline__ unsigned short f2bf(float f) {
  // RNE f32 -> bf16 (inputs finite)
  unsigned int u = __builtin_bit_cast(unsigned int, f);
  unsigned int r = u + 0x7FFFu + ((u >> 16) & 1u);
  return (unsigned short)(r >> 16);
}

// ---------------- prep kernel (parallel, ~few us) ----------------
// blocks 0..191: wdT[k][d] = bf16(gamma[d]*Wd[d][k]); wuT[d][k] = bf16(Wu[k][d])
// block 192: s[k], t[k] partial-sum reduction
__global__ void adapter_prep(const float* __restrict__ wd,
                             const float* __restrict__ wu,
                             const float* __restrict__ gamma,
                             const float* __restrict__ beta,
                             const float* __restrict__ bdown,
                             unsigned short* __restrict__ wdT,
                             unsigned short* __restrict__ wuT,
                             float* __restrict__ s_arr,
                             float* __restrict__ t_arr) {
  const int b = blockIdx.x;
  const int t = threadIdx.x;
  if (b < 192) {
    const int i = b * 256 + t;          // 0..49151
    const int k1 = i / D_MODEL;
    const int d1 = i - k1 * D_MODEL;
    wdT[i] = f2bf(gamma[d1] * wd[(size_t)d1 * KB + k1]);
    const int d2 = i >> 6;
    const int k2 = i & 63;
    wuT[i] = f2bf(wu[(size_t)k2 * D_MODEL + d2]);
  } else {
    const int k = t & 63;
    const int c = t >> 6;
    float ss = 0.f, tt = 0.f;
    const int d0 = c * 192;
    #pragma unroll 4
    for (int d = d0; d < d0 + 192; ++d) {
      const float w = wd[(size_t)d * KB + k];
      ss = fmaf(gamma[d], w, ss);
      tt = fmaf(beta[d],  w, tt);
    }
    __shared__ float ps[4][64], pt[4][64];
    ps[c][k] = ss; pt[c][k] = tt;
    __syncthreads();
    if (t < 64) {
      s_arr[t] = ps[0][t] + ps[1][t] + ps[2][t] + ps[3][t];
      t_arr[t] = pt[0][t] + pt[1][t] + pt[2][t] + pt[3][t] + bdown[t];
    }
  }
}

// ---------------- main fused kernel ----------------
__global__ void __launch_bounds__(NTHR, 4) adapter_main(
    const float* __restrict__ x,
    const float* __restrict__ s_arr,
    const float* __restrict__ t_arr,
    const unsigned short* __restrict__ wdT,
    const unsigned short* __restrict__ wuT,
    const float* __restrict__ b_up,
    float* __restrict__ out) {

  __shared__ unsigned short p_s[4][16][PPAD];   // 9 KiB, per-wave private patches

  const int t   = threadIdx.x;
  const int wid = t >> 6;
  const int l   = t & 63;
  const int lr  = l & 15;      // fragment lane index
  const int lg  = l >> 4;      // k-group
  const int row0 = blockIdx.x * 64 + wid * 16;   // this wave's 16 rows

  // ---- GEMM1 (swapped): acc_c = (gamma⊙Wd)^T-tile_c · x^T ; stats inline ----
  // A-frag c: lane -> wdT[16c+lr][32kk+8lg+e]
  // B-frag:   lane -> x[row0+lr][32kk+8lg+e]   (HBM, 16 full lines per instr)
  // C layout: lane reg j -> down[row lr][col 16c+4lg+j]
  const float* xp = x + (size_t)(row0 + lr) * D_MODEL + 8 * lg;
  const unsigned short* wp = wdT + (size_t)lr * D_MODEL + 8 * lg;

  f32x4 acc0 = {0.f,0.f,0.f,0.f}, acc1 = {0.f,0.f,0.f,0.f};
  f32x4 acc2 = {0.f,0.f,0.f,0.f}, acc3 = {0.f,0.f,0.f,0.f};
  float s1 = 0.f, s2 = 0.f;

  #pragma unroll
  for (int kk = 0; kk < 24; ++kk) {
    const float4 v0 = *(const float4*)(xp + 32 * kk);
    const float4 v1 = *(const float4*)(xp + 32 * kk + 4);
    s1 += (v0.x + v0.y) + (v0.z + v0.w) + (v1.x + v1.y) + (v1.z + v1.w);
    s2 = fmaf(v0.x, v0.x, s2); s2 = fmaf(v0.y, v0.y, s2);
    s2 = fmaf(v0.z, v0.z, s2); s2 = fmaf(v0.w, v0.w, s2);
    s2 = fmaf(v1.x, v1.x, s2); s2 = fmaf(v1.y, v1.y, s2);
    s2 = fmaf(v1.z, v1.z, s2); s2 = fmaf(v1.w, v1.w, s2);
    bf16x8 xf;
    xf[0] = (short)f2bf(v0.x); xf[1] = (short)f2bf(v0.y);
    xf[2] = (short)f2bf(v0.z); xf[3] = (short)f2bf(v0.w);
    xf[4] = (short)f2bf(v1.x); xf[5] = (short)f2bf(v1.y);
    xf[6] = (short)f2bf(v1.z); xf[7] = (short)f2bf(v1.w);
    const bf16x8 wa0 = *(const bf16x8*)(wp + 32 * kk);
    const bf16x8 wa1 = *(const bf16x8*)(wp + 16 * D_MODEL + 32 * kk);
    const bf16x8 wa2 = *(const bf16x8*)(wp + 32 * D_MODEL + 32 * kk);
    const bf16x8 wa3 = *(const bf16x8*)(wp + 48 * D_MODEL + 32 * kk);
    acc0 = __builtin_amdgcn_mfma_f32_16x16x32_bf16(wa0, xf, acc0, 0, 0, 0);
    acc1 = __builtin_amdgcn_mfma_f32_16x16x32_bf16(wa1, xf, acc1, 0, 0, 0);
    acc2 = __builtin_amdgcn_mfma_f32_16x16x32_bf16(wa2, xf, acc2, 0, 0, 0);
    acc3 = __builtin_amdgcn_mfma_f32_16x16x32_bf16(wa3, xf, acc3, 0, 0, 0);
  }

  // ---- LN stats: row lr's full sum lives in lanes {lr, lr+16, lr+32, lr+48} ----
  s1 += __shfl_xor(s1, 16); s1 += __shfl_xor(s1, 32);
  s2 += __shfl_xor(s2, 16); s2 += __shfl_xor(s2, 32);
  const float mu  = s1 * (1.0f / 768.0f);
  const float var = s2 * (1.0f / 768.0f) - mu * mu;
  const float rs  = rsqrtf(var + 1e-5f);
  const float nm  = -rs * mu;

  // ---- epilogue: LN correction + ReLU + bf16, write P^ tile to LDS ----
  // lane reg j is down[row lr][col 16c+4lg+j] -> pack 4 consecutive cols
  #pragma unroll
  for (int c = 0; c < 4; ++c) {
    const f32x4 a = (c == 0) ? acc0 : (c == 1) ? acc1 : (c == 2) ? acc2 : acc3;
    const float4 sv = *(const float4*)(s_arr + 16 * c + 4 * lg);
    const float4 tv = *(const float4*)(t_arr + 16 * c + 4 * lg);
    us4 pk;
    pk.x = f2bf(fmaxf(fmaf(rs, a[0], fmaf(nm, sv.x, tv.x)), 0.f));
    pk.y = f2bf(fmaxf(fmaf(rs, a[1], fmaf(nm, sv.y, tv.y)), 0.f));
    pk.z = f2bf(fmaxf(fmaf(rs, a[2], fmaf(nm, sv.z, tv.z)), 0.f));
    pk.w = f2bf(fmaxf(fmaf(rs, a[3], fmaf(nm, sv.w, tv.w)), 0.f));
    *(us4*)&p_s[wid][lr][16 * c + 4 * lg] = pk;   // ds_write_b64, conflict-free
  }

  // cheap safety barrier (cross-LANE LDS reuse within wave; also orders waves)
  __syncthreads();

  // ---- GEMM2: out rows = P(16x64) @ Wu ; wave covers all 48 N-tiles ----
  const bf16x8 pa0 = *(const bf16x8*)&p_s[wid][lr][8 * lg];        // k 0..31
  const bf16x8 pa1 = *(const bf16x8*)&p_s[wid][lr][32 + 8 * lg];   // k 32..63
  float* op = out + (size_t)(row0 + 4 * lg) * D_MODEL + lr;

  #pragma unroll 4
  for (int n = 0; n < 48; ++n) {
    const int cn = 16 * n;
    const unsigned short* bp = wuT + (size_t)(cn + lr) * KB + 8 * lg;
    f32x4 c0 = {0.f, 0.f, 0.f, 0.f};
    c0 = __builtin_amdgcn_mfma_f32_16x16x32_bf16(pa0, *(const bf16x8*)(bp), c0, 0, 0, 0);
    c0 = __builtin_amdgcn_mfma_f32_16x16x32_bf16(pa1, *(const bf16x8*)(bp + 32), c0, 0, 0, 0);
    const float bu = b_up[cn + lr];
    op[(size_t)0 * D_MODEL + cn] = c0[0] + bu;
    op[(size_t)1 * D_MODEL + cn] = c0[1] + bu;
    op[(size_t)2 * D_MODEL + cn] = c0[2] + bu;
    op[(size_t)3 * D_MODEL + cn] = c0[3] + bu;
  }
}

// ---------------- launch ----------------
extern "C" void kernel_launch(void* const* d_in, const int* in_sizes, int n_in,
                              void* d_out, int out_size, void* d_ws, size_t ws_size,
                              hipStream_t stream) {
  const float* x     = (const float*)d_in[0];
  const float* gamma = (const float*)d_in[1];
  const float* beta  = (const float*)d_in[2];
  const float* wd    = (const float*)d_in[3];
  const float* bdown = (const float*)d_in[4];
  const float* wu    = (const float*)d_in[5];
  const float* bup   = (const float*)d_in[6];
  float* out = (float*)d_out;

  char* ws = (char*)d_ws;
  unsigned short* wdT = (unsigned short*)ws;                    // 96 KiB
  unsigned short* wuT = (unsigned short*)(ws + 98304);          // 96 KiB
  float* s_arr = (float*)(ws + 196608);                         // 256 B
  float* t_arr = (float*)(ws + 196864);                         // 256 B

  const int rows = in_sizes[0] / D_MODEL;       // 32768

  adapter_prep<<<193, NTHR, 0, stream>>>(wd, wu, gamma, beta, bdown,
                                         wdT, wuT, s_arr, t_arr);
  adapter_main<<<rows / 64, NTHR, 0, stream>>>(x, s_arr, t_arr, wdT, wuT, bup, out);
}

// Round 4
// 221.929 us; speedup vs baseline: 1.0879x; 1.0118x over previous
//
#include <hip/hip_runtime.h>
#include <hip/hip_bf16.h>

// Fused adapter: out = relu(LN(x) @ Wd + bd) @ Wu + bu
// LN folded into GEMM1:  down = rs*(x @ (gamma⊙Wd)) - rs*mu*s + t
// R4: R3's per-wave streaming structure + deep explicit software pipelining.
// R3 counters showed VGPR=40 => compiler kept no loads in flight; kernel was
// pure latency-bound at 1.9 TB/s with 2 waves/SIMD (decomposition-fixed).
//  - GEMM1: 6 chunks x 4 kk; double-buffered register x-buffer (8 float4 in
//    flight per wave), weight frags rolled 2-kk ahead (covers L2 ~200cyc)
//  - GEMM2: 8 chunks x 6 N-tiles, double-buffered weight/bias regs
//  - launch_bounds(256,2): 256-VGPR budget, still 2 waves/SIMD
//  - no __syncthreads at all (P-bounce LDS is wave-private)

#define D_MODEL 768
#define KB      64
#define NTHR    256     // 4 waves, each an independent 16-row tile
#define PPAD    72      // 64 + 8 bf16 pad

#define CH1     4       // kk-steps per GEMM1 chunk (24 total -> 6 chunks)
#define NCH1    6
#define CH2     6       // N-tiles per GEMM2 chunk (48 total -> 8 chunks)
#define NCH2    8

typedef __attribute__((ext_vector_type(8))) short    bf16x8;
typedef __attribute__((ext_vector_type(4))) float    f32x4;
typedef __attribute__((ext_vector_type(4))) unsigned short us4;

static __device__ __forceinline__ unsigned short f2bf(float f) {
  // RNE f32 -> bf16 (inputs finite)
  unsigned int u = __builtin_bit_cast(unsigned int, f);
  unsigned int r = u + 0x7FFFu + ((u >> 16) & 1u);
  return (unsigned short)(r >> 16);
}

// ---------------- prep kernel: 49 blocks x 1024 thr ----------------
// blocks 0..47: wdT[k][d] = bf16(gamma[d]*Wd[d][k]); wuT[d][k] = bf16(Wu[k][d])
// block 48: s[k] = sum_d gamma[d]*Wd[d][k]; t[k] = sum_d beta[d]*Wd[d][k]+bd[k]
__global__ void __launch_bounds__(1024) adapter_prep(
    const float* __restrict__ wd,
    const float* __restrict__ wu,
    const float* __restrict__ gamma,
    const float* __restrict__ beta,
    const float* __restrict__ bdown,
    unsigned short* __restrict__ wdT,
    unsigned short* __restrict__ wuT,
    float* __restrict__ s_arr,
    float* __restrict__ t_arr) {
  const int b = blockIdx.x;
  const int t = threadIdx.x;
  if (b < 48) {
    const int i = b * 1024 + t;         // 0..49151
    const int k1 = i / D_MODEL;
    const int d1 = i - k1 * D_MODEL;
    wdT[i] = f2bf(gamma[d1] * wd[(size_t)d1 * KB + k1]);
    const int d2 = i >> 6;
    const int k2 = i & 63;
    wuT[i] = f2bf(wu[(size_t)k2 * D_MODEL + d2]);
  } else {
    const int k = t & 63;
    const int c = t >> 6;               // 0..15, 48 d's each
    float ss = 0.f, tt = 0.f;
    const int d0 = c * 48;
    #pragma unroll 4
    for (int d = d0; d < d0 + 48; ++d) {
      const float w = wd[(size_t)d * KB + k];
      ss = fmaf(gamma[d], w, ss);
      tt = fmaf(beta[d],  w, tt);
    }
    __shared__ float ps[16][64], pt[16][64];
    ps[c][k] = ss; pt[c][k] = tt;
    __syncthreads();
    if (t < 64) {
      float S = 0.f, T = 0.f;
      #pragma unroll
      for (int q = 0; q < 16; ++q) { S += ps[q][t]; T += pt[q][t]; }
      s_arr[t] = S;
      t_arr[t] = T + bdown[t];
    }
  }
}

// ---------------- main fused kernel ----------------
__global__ void __launch_bounds__(NTHR, 2) adapter_main(
    const float* __restrict__ x,
    const float* __restrict__ s_arr,
    const float* __restrict__ t_arr,
    const unsigned short* __restrict__ wdT,
    const unsigned short* __restrict__ wuT,
    const float* __restrict__ b_up,
    float* __restrict__ out) {

  __shared__ unsigned short p_s[4][16][PPAD];   // 9 KiB, wave-private patches

  const int t   = threadIdx.x;
  const int wid = t >> 6;
  const int l   = t & 63;
  const int lr  = l & 15;      // fragment lane index
  const int lg  = l >> 4;      // k-group
  const int row0 = blockIdx.x * 64 + wid * 16;  // this wave's 16 rows

  // ======== GEMM1 (swapped): down^T tiles; LN stats inline ========
  // A-frag c: wdT[16c+lr][32kk+8lg+e];  B-frag: x[row0+lr][32kk+8lg+e]
  // D: lane reg j -> down[row lr][col 16c+4lg+j]
  const float* xp = x + (size_t)(row0 + lr) * D_MODEL + 8 * lg;
  const unsigned short* wp = wdT + (size_t)lr * D_MODEL + 8 * lg;

  f32x4 acc[4];
  #pragma unroll
  for (int c = 0; c < 4; ++c) acc[c] = (f32x4){0.f, 0.f, 0.f, 0.f};
  float s1 = 0.f, s2 = 0.f;

  float4 xb[2][CH1][2];
  bf16x8 wf[2][4];

  // preload x chunk 0 (8 loads in flight)
  #pragma unroll
  for (int j = 0; j < CH1; ++j) {
    xb[0][j][0] = *(const float4*)(xp + 32 * j);
    xb[0][j][1] = *(const float4*)(xp + 32 * j + 4);
  }
  // preload weight frags for kk = 0, 1
  #pragma unroll
  for (int c = 0; c < 4; ++c) {
    wf[0][c] = *(const bf16x8*)(wp + (size_t)16 * c * D_MODEL);
    wf[1][c] = *(const bf16x8*)(wp + (size_t)16 * c * D_MODEL + 32);
  }

  #pragma unroll
  for (int ch = 0; ch < NCH1; ++ch) {
    const int cur = ch & 1, nxt = cur ^ 1;
    if (ch < NCH1 - 1) {          // issue next chunk's x loads first
      #pragma unroll
      for (int j = 0; j < CH1; ++j) {
        xb[nxt][j][0] = *(const float4*)(xp + 32 * (CH1 * (ch + 1) + j));
        xb[nxt][j][1] = *(const float4*)(xp + 32 * (CH1 * (ch + 1) + j) + 4);
      }
    }
    #pragma unroll
    for (int j = 0; j < CH1; ++j) {
      const int kk = CH1 * ch + j;
      const float4 v0 = xb[cur][j][0];
      const float4 v1 = xb[cur][j][1];
      s1 += (v0.x + v0.y) + (v0.z + v0.w) + (v1.x + v1.y) + (v1.z + v1.w);
      s2 = fmaf(v0.x, v0.x, s2); s2 = fmaf(v0.y, v0.y, s2);
      s2 = fmaf(v0.z, v0.z, s2); s2 = fmaf(v0.w, v0.w, s2);
      s2 = fmaf(v1.x, v1.x, s2); s2 = fmaf(v1.y, v1.y, s2);
      s2 = fmaf(v1.z, v1.z, s2); s2 = fmaf(v1.w, v1.w, s2);
      bf16x8 xf;
      xf[0] = (short)f2bf(v0.x); xf[1] = (short)f2bf(v0.y);
      xf[2] = (short)f2bf(v0.z); xf[3] = (short)f2bf(v0.w);
      xf[4] = (short)f2bf(v1.x); xf[5] = (short)f2bf(v1.y);
      xf[6] = (short)f2bf(v1.z); xf[7] = (short)f2bf(v1.w);
      #pragma unroll
      for (int c = 0; c < 4; ++c)
        acc[c] = __builtin_amdgcn_mfma_f32_16x16x32_bf16(wf[kk & 1][c], xf, acc[c], 0, 0, 0);
      if (kk + 2 < 24) {          // roll weight window 2-kk ahead
        #pragma unroll
        for (int c = 0; c < 4; ++c)
          wf[kk & 1][c] = *(const bf16x8*)(wp + (size_t)16 * c * D_MODEL + 32 * (kk + 2));
      }
    }
  }

  // ---- LN stats: row lr's sums live in lanes {lr, lr+16, lr+32, lr+48} ----
  s1 += __shfl_xor(s1, 16); s1 += __shfl_xor(s1, 32);
  s2 += __shfl_xor(s2, 16); s2 += __shfl_xor(s2, 32);
  const float mu  = s1 * (1.0f / 768.0f);
  const float var = s2 * (1.0f / 768.0f) - mu * mu;
  const float rs  = rsqrtf(var + 1e-5f);
  const float nm  = -rs * mu;

  // ---- epilogue: LN correction + ReLU + bf16 -> wave-private LDS patch ----
  #pragma unroll
  for (int c = 0; c < 4; ++c) {
    const float4 sv = *(const float4*)(s_arr + 16 * c + 4 * lg);
    const float4 tv = *(const float4*)(t_arr + 16 * c + 4 * lg);
    us4 pk;
    pk.x = f2bf(fmaxf(fmaf(rs, acc[c][0], fmaf(nm, sv.x, tv.x)), 0.f));
    pk.y = f2bf(fmaxf(fmaf(rs, acc[c][1], fmaf(nm, sv.y, tv.y)), 0.f));
    pk.z = f2bf(fmaxf(fmaf(rs, acc[c][2], fmaf(nm, sv.z, tv.z)), 0.f));
    pk.w = f2bf(fmaxf(fmaf(rs, acc[c][3], fmaf(nm, sv.w, tv.w)), 0.f));
    *(us4*)&p_s[wid][lr][16 * c + 4 * lg] = pk;
  }
  // no barrier: patch is wave-private; compiler inserts the lgkmcnt wait

  // ======== GEMM2: out rows = P(16x64) @ Wu, 48 N-tiles, double-buffered ====
  const bf16x8 pa0 = *(const bf16x8*)&p_s[wid][lr][8 * lg];        // k 0..31
  const bf16x8 pa1 = *(const bf16x8*)&p_s[wid][lr][32 + 8 * lg];   // k 32..63
  float* op = out + (size_t)(row0 + 4 * lg) * D_MODEL + lr;

  bf16x8 wb[2][CH2][2];
  float  bb[2][CH2];
  #pragma unroll
  for (int j = 0; j < CH2; ++j) {
    const int cn = 16 * j;
    const unsigned short* bp = wuT + (size_t)(cn + lr) * KB + 8 * lg;
    wb[0][j][0] = *(const bf16x8*)(bp);
    wb[0][j][1] = *(const bf16x8*)(bp + 32);
    bb[0][j]    = b_up[cn + lr];
  }

  #pragma unroll
  for (int ch = 0; ch < NCH2; ++ch) {
    const int cur = ch & 1, nxt = cur ^ 1;
    if (ch < NCH2 - 1) {
      #pragma unroll
      for (int j = 0; j < CH2; ++j) {
        const int cn = 16 * (CH2 * (ch + 1) + j);
        const unsigned short* bp = wuT + (size_t)(cn + lr) * KB + 8 * lg;
        wb[nxt][j][0] = *(const bf16x8*)(bp);
        wb[nxt][j][1] = *(const bf16x8*)(bp + 32);
        bb[nxt][j]    = b_up[cn + lr];
      }
    }
    #pragma unroll
    for (int j = 0; j < CH2; ++j) {
      const int cn = 16 * (CH2 * ch + j);
      f32x4 c0 = {0.f, 0.f, 0.f, 0.f};
      c0 = __builtin_amdgcn_mfma_f32_16x16x32_bf16(pa0, wb[cur][j][0], c0, 0, 0, 0);
      c0 = __builtin_amdgcn_mfma_f32_16x16x32_bf16(pa1, wb[cur][j][1], c0, 0, 0, 0);
      const float bu = bb[cur][j];
      op[(size_t)0 * D_MODEL + cn] = c0[0] + bu;
      op[(size_t)1 * D_MODEL + cn] = c0[1] + bu;
      op[(size_t)2 * D_MODEL + cn] = c0[2] + bu;
      op[(size_t)3 * D_MODEL + cn] = c0[3] + bu;
    }
  }
}

// ---------------- launch ----------------
extern "C" void kernel_launch(void* const* d_in, const int* in_sizes, int n_in,
                              void* d_out, int out_size, void* d_ws, size_t ws_size,
                              hipStream_t stream) {
  const float* x     = (const float*)d_in[0];
  const float* gamma = (const float*)d_in[1];
  const float* beta  = (const float*)d_in[2];
  const float* wd    = (const float*)d_in[3];
  const float* bdown = (const float*)d_in[4];
  const float* wu    = (const float*)d_in[5];
  const float* bup   = (const float*)d_in[6];
  float* out = (float*)d_out;

  char* ws = (char*)d_ws;
  unsigned short* wdT = (unsigned short*)ws;                    // 96 KiB
  unsigned short* wuT = (unsigned short*)(ws + 98304);          // 96 KiB
  float* s_arr = (float*)(ws + 196608);                         // 256 B
  float* t_arr = (float*)(ws + 196864);                         // 256 B

  const int rows = in_sizes[0] / D_MODEL;       // 32768

  adapter_prep<<<49, 1024, 0, stream>>>(wd, wu, gamma, beta, bdown,
                                        wdT, wuT, s_arr, t_arr);
  adapter_main<<<rows / 64, NTHR, 0, stream>>>(x, s_arr, t_arr, wdT, wuT, bup, out);
}